// Round 6
// baseline (281.408 us; speedup 1.0000x reference)
//
#include <hip/hip_runtime.h>
#include <hip/hip_fp16.h>

#define NN 50000
#define NM 50000
#define F  128
#define NBUK 782      // ceil(50000/64) buckets of 64 dest ids
#define CHSZ 8192     // edges per sort chunk
#define GROWS 12      // gemm rows per block
typedef unsigned short ushort_t;

// ---------------- block-scan helpers ---------------------------------------------
__device__ __forceinline__ int wscan64(int v, int lane) {
    int x = v;
#pragma unroll
    for (int s = 1; s < 64; s <<= 1) {
        int u = __shfl_up(x, s, 64);
        if (lane >= s) x += u;
    }
    return x;   // inclusive
}

__device__ __forceinline__ int bscan256(int v, int* s5, int* tot) {
    int t = threadIdx.x, lane = t & 63, wid = t >> 6;
    int incl = wscan64(v, lane);
    if (lane == 63) s5[wid] = incl;
    __syncthreads();
    if (t == 0) {
        int a = 0;
#pragma unroll
        for (int j = 0; j < 4; ++j) { int x = s5[j]; s5[j] = a; a += x; }
        s5[4] = a;
    }
    __syncthreads();
    int ex = incl - v + s5[wid];
    *tot = s5[4];
    __syncthreads();
    return ex;
}

// ---------------- fat kernel: chunksort blocks [0,nsort) + gemm blocks -----------
struct GemmSmem { __half sWh[128 * 128]; float sX[GROWS * 128]; };   // 32KB + 6KB
struct SortSmem { int hist[NBUK]; int cursor[NBUK]; int pairs[CHSZ]; int s5[5]; }; // 39KB
union alignas(16) FatSmem { GemmSmem g; SortSmem s; };

__global__ __launch_bounds__(256) void fat_k(const float* __restrict__ X,
                                             const float* __restrict__ W,
                                             __half2* __restrict__ xs,     // sliced x table
                                             const int* __restrict__ nodes,
                                             const int* __restrict__ hedges,
                                             int* __restrict__ gchunk0, int* __restrict__ gchunk1,
                                             int* __restrict__ ghist, int* __restrict__ gstart,
                                             int E, int NCH, int nsort) {
    __shared__ FatSmem u;
    int t = threadIdx.x;

    if ((int)blockIdx.x < nsort) {
        // ---------------- chunksort ----------------
        int dir = blockIdx.x / NCH;
        int c   = blockIdx.x % NCH;
        const int* key = dir ? nodes  : hedges;
        const int* pay = dir ? hedges : nodes;
        int* gchunk    = dir ? gchunk1 : gchunk0;
        int e0 = c * CHSZ, e1 = min(E, e0 + CHSZ);

        for (int i = t; i < NBUK; i += 256) u.s.hist[i] = 0;
        __syncthreads();
        for (int e = e0 + t; e < e1; e += 256) atomicAdd(&u.s.hist[key[e] >> 6], 1);
        __syncthreads();

        int carry = 0;
        for (int base = 0; base < NBUK; base += 256) {
            int i = base + t;
            int v = (i < NBUK) ? u.s.hist[i] : 0;
            int tot;
            int ex = bscan256(v, u.s.s5, &tot);
            if (i < NBUK) u.s.cursor[i] = ex + carry;
            carry += tot;
        }
        __syncthreads();

        for (int b = t; b < NBUK; b += 256) {
            size_t idx = ((size_t)dir * NBUK + b) * NCH + c;
            ghist[idx]  = u.s.hist[b];
            gstart[idx] = u.s.cursor[b];
        }
        __syncthreads();

        for (int e = e0 + t; e < e1; e += 256) {
            int k = key[e];
            int pos = atomicAdd(&u.s.cursor[k >> 6], 1);
            u.s.pairs[pos] = ((k & 63) << 16) | pay[e];
        }
        __syncthreads();

        int n = e1 - e0;
        for (int i = t; i < n; i += 256) gchunk[(size_t)c * CHSZ + i] = u.s.pairs[i];
    } else {
        // ---------------- gemm: x = X @ W -> fp16 sliced table ----------------
        int gb = blockIdx.x - nsort;

        // stage W as half2 pairs: sWh2[k*64 + l] = (W[k][2l], W[k][2l+1])
        __half2* sWh2 = (__half2*)u.g.sWh;
        for (int i = t; i < 4096; i += 256) {
            float4 wv = ((const float4*)W)[i];
            int k = i >> 5, cc = i & 31;
            sWh2[k * 64 + 2 * cc]     = __floats2half2_rn(wv.x, wv.y);
            sWh2[k * 64 + 2 * cc + 1] = __floats2half2_rn(wv.z, wv.w);
        }
        // stage X tile (GROWS rows), zero-fill past end
        const float4* X4 = (const float4*)X;
        size_t gbase = (size_t)gb * GROWS * 32;
        for (int i = t; i < GROWS * 32; i += 256) {
            size_t gi = gbase + i;
            ((float4*)u.g.sX)[i] = (gi < (size_t)NN * 32) ? X4[gi] : make_float4(0.f, 0.f, 0.f, 0.f);
        }
        __syncthreads();

        int l = t & 63, w = t >> 6;           // lane owns col pair (2l,2l+1); wave owns 3 rows
        float acc[3][2] = {};
        for (int k0 = 0; k0 < 128; k0 += 4) {
            float4 xr0 = *(const float4*)&u.g.sX[(w * 3 + 0) * 128 + k0];
            float4 xr1 = *(const float4*)&u.g.sX[(w * 3 + 1) * 128 + k0];
            float4 xr2 = *(const float4*)&u.g.sX[(w * 3 + 2) * 128 + k0];
            const float* x0 = (const float*)&xr0;
            const float* x1 = (const float*)&xr1;
            const float* x2p = (const float*)&xr2;
#pragma unroll
            for (int j = 0; j < 4; ++j) {
                float2 wv = __half22float2(sWh2[(k0 + j) * 64 + l]);
                acc[0][0] = fmaf(x0[j], wv.x, acc[0][0]); acc[0][1] = fmaf(x0[j], wv.y, acc[0][1]);
                acc[1][0] = fmaf(x1[j], wv.x, acc[1][0]); acc[1][1] = fmaf(x1[j], wv.y, acc[1][1]);
                acc[2][0] = fmaf(x2p[j], wv.x, acc[2][0]); acc[2][1] = fmaf(x2p[j], wv.y, acc[2][1]);
            }
        }
        int s = l >> 3, cc = l & 7;           // slice, half2-col within slice
#pragma unroll
        for (int r = 0; r < 3; ++r) {
            int row = gb * GROWS + w * 3 + r;
            if (row < NN)
                xs[((size_t)s * NN + row) * 8 + cc] = __floats2half2_rn(acc[r][0], acc[r][1]);
        }
    }
}

// ---------------- 2: bucket totals -> global bucket starts -----------------------
__global__ __launch_bounds__(1024) void bucketbase_k(const int* __restrict__ ghist,
                                                     int* __restrict__ bstart,
                                                     int* __restrict__ off0, int* __restrict__ off1,
                                                     int E, int NCH) {
    __shared__ int s16[17];
    int dir = blockIdx.x;
    int t = threadIdx.x, lane = t & 63, wid = t >> 6;
    int v = 0;
    if (t < NBUK) {
        const int* row = ghist + ((size_t)dir * NBUK + t) * NCH;
        int s = 0;
#pragma unroll 4
        for (int c = 0; c < NCH; ++c) s += row[c];
        v = s;
    }
    int incl = wscan64(v, lane);
    if (lane == 63) s16[wid] = incl;
    __syncthreads();
    if (t < 16) {
        int x = s16[t], y = x;
#pragma unroll
        for (int s = 1; s < 16; s <<= 1) {
            int u = __shfl_up(y, s, 64);
            if (t >= s) y += u;
        }
        s16[t] = y - x;
    }
    __syncthreads();
    int ex = incl - v + s16[wid];
    if (t < NBUK) bstart[dir * NBUK + t] = ex;
    if (t == 0) (dir ? off1 : off0)[50000] = E;
}

// ---------------- 3: per-bucket merge + fine sort + scatter ----------------------
__global__ __launch_bounds__(256) void merge_scatter_k(const int* __restrict__ gchunk0, const int* __restrict__ gchunk1,
                                                       const int* __restrict__ ghist, const int* __restrict__ gstart,
                                                       const int* __restrict__ bstart,
                                                       ushort_t* __restrict__ adj0, ushort_t* __restrict__ adj1,
                                                       int* __restrict__ off0, int* __restrict__ off1,
                                                       int NCH) {
    __shared__ int ssrc[256];
    __shared__ int sdst[257];
    __shared__ int s5[5];
    __shared__ int pairsS[CHSZ];
    __shared__ int fcnt[64], foff[64], fcur[64];

    int dir = blockIdx.x / NBUK;
    int b   = blockIdx.x % NBUK;
    int t   = threadIdx.x;
    const int* gchunk   = dir ? gchunk1 : gchunk0;
    ushort_t* adj       = dir ? adj1 : adj0;
    int* offD           = dir ? off1 : off0;

    int len = 0, src = 0;
    if (t < NCH) {
        size_t idx = ((size_t)dir * NBUK + b) * NCH + t;
        len = ghist[idx];
        src = gstart[idx];
    }
    ssrc[t] = src;
    int tot;
    int ex = bscan256(len, s5, &tot);
    sdst[t] = ex;
    if (t == 0) sdst[256] = 0x7FFFFFFF;
    if (t < 64) fcnt[t] = 0;
    __syncthreads();
    int T = tot;

    int per = (T + 255) >> 8;
    int i0 = t * per, i1 = min(T, i0 + per);
    if (i0 < i1) {
        int lo = 0, hi = 255;
        while (lo < hi) {
            int mid = (lo + hi + 1) >> 1;
            if (sdst[mid] <= i0) lo = mid; else hi = mid - 1;
        }
        int c = lo;
        for (int i = i0; i < i1; ++i) {
            while (c < 255 && sdst[c + 1] <= i) ++c;
            int p = gchunk[(size_t)c * CHSZ + ssrc[c] + (i - sdst[c])];
            pairsS[i] = p;
            atomicAdd(&fcnt[p >> 16], 1);
        }
    }
    __syncthreads();

    int bst = bstart[dir * NBUK + b];
    if (t < 64) {
        int x = fcnt[t];
        int y = wscan64(x, t);
        foff[t] = y - x;
        fcur[t] = y - x;
        int d = b * 64 + t;
        if (d < 50000) offD[d] = bst + foff[t];
    }
    __syncthreads();

    for (int i = t; i < T; i += 256) {
        int p = pairsS[i];
        int slot = atomicAdd(&fcur[p >> 16], 1);
        adj[(size_t)bst + slot] = (ushort_t)(p & 0xFFFF);
    }
}

// ---------------- pass A (sliced): m_s[h] = B_inv * sum x_s[v] -------------------
// grid = 8 slices * ceil(NM/32); slice = bid&7 -> XCD-local table slice
__global__ __launch_bounds__(256) void agg_a_k(const __half2* __restrict__ xs,
                                               const ushort_t* __restrict__ adj,
                                               const int* __restrict__ off,
                                               __half2* __restrict__ ms) {
    int t = threadIdx.x;
    int s = blockIdx.x & 7;
    int seg = (blockIdx.x >> 3) * 32 + (t >> 3);
    int c = t & 7;
    if (seg >= NM) return;
    int p0 = off[seg], p1 = off[seg + 1];
    const __half2* base = xs + (size_t)s * NN * 8 + c;
    float ax = 0.f, ay = 0.f, bx = 0.f, by = 0.f;
    int i = p0;
    for (; i + 4 <= p1; i += 4) {
        int n0 = adj[i], n1 = adj[i + 1], n2 = adj[i + 2], n3 = adj[i + 3];
        float2 v0 = __half22float2(base[(size_t)n0 * 8]);
        float2 v1 = __half22float2(base[(size_t)n1 * 8]);
        float2 v2 = __half22float2(base[(size_t)n2 * 8]);
        float2 v3 = __half22float2(base[(size_t)n3 * 8]);
        ax += v0.x; ay += v0.y; bx += v1.x; by += v1.y;
        ax += v2.x; ay += v2.y; bx += v3.x; by += v3.y;
    }
    for (; i < p1; ++i) {
        float2 v = __half22float2(base[(size_t)adj[i] * 8]);
        ax += v.x; ay += v.y;
    }
    float inv = (p1 > p0) ? 1.0f / (float)(p1 - p0) : 0.0f;
    ms[((size_t)s * NM + seg) * 8 + c] = __floats2half2_rn((ax + bx) * inv, (ay + by) * inv);
}

// ---------------- pass B (sliced): logits_s[v] = D_inv * sum m_s[h] + b_s --------
__global__ __launch_bounds__(256) void agg_b_k(const __half2* __restrict__ ms,
                                               const ushort_t* __restrict__ adj,
                                               const int* __restrict__ off,
                                               const float* __restrict__ bias,
                                               float2* __restrict__ lg) {
    int t = threadIdx.x;
    int s = blockIdx.x & 7;
    int seg = (blockIdx.x >> 3) * 32 + (t >> 3);
    int c = t & 7;
    if (seg >= NN) return;
    int p0 = off[seg], p1 = off[seg + 1];
    const __half2* base = ms + (size_t)s * NM * 8 + c;
    float ax = 0.f, ay = 0.f, bx = 0.f, by = 0.f;
    int i = p0;
    for (; i + 4 <= p1; i += 4) {
        int n0 = adj[i], n1 = adj[i + 1], n2 = adj[i + 2], n3 = adj[i + 3];
        float2 v0 = __half22float2(base[(size_t)n0 * 8]);
        float2 v1 = __half22float2(base[(size_t)n1 * 8]);
        float2 v2 = __half22float2(base[(size_t)n2 * 8]);
        float2 v3 = __half22float2(base[(size_t)n3 * 8]);
        ax += v0.x; ay += v0.y; bx += v1.x; by += v1.y;
        ax += v2.x; ay += v2.y; bx += v3.x; by += v3.y;
    }
    for (; i < p1; ++i) {
        float2 v = __half22float2(base[(size_t)adj[i] * 8]);
        ax += v.x; ay += v.y;
    }
    float inv = (p1 > p0) ? 1.0f / (float)(p1 - p0) : 0.0f;
    float2 bb = ((const float2*)bias)[s * 8 + c];
    lg[((size_t)s * NN + seg) * 8 + c] = make_float2((ax + bx) * inv + bb.x,
                                                     (ay + by) * inv + bb.y);
}

// ---------------- final: row softmax from sliced logits -> d_out -----------------
__global__ __launch_bounds__(256) void softmax_k(const float2* __restrict__ lg,
                                                 float2* __restrict__ out) {
    int v = blockIdx.x * 4 + (threadIdx.x >> 6);
    int l = threadIdx.x & 63;
    float2 val = lg[((size_t)(l >> 3) * NN + v) * 8 + (l & 7)];
    float mx = fmaxf(val.x, val.y);
#pragma unroll
    for (int s2 = 32; s2 >= 1; s2 >>= 1) mx = fmaxf(mx, __shfl_xor(mx, s2, 64));
    float e0 = __expf(val.x - mx), e1 = __expf(val.y - mx);
    float sm = e0 + e1;
#pragma unroll
    for (int s2 = 32; s2 >= 1; s2 >>= 1) sm += __shfl_xor(sm, s2, 64);
    float r = 1.0f / sm;
    out[(size_t)v * 64 + l] = make_float2(e0 * r, e1 * r);
}

// ---------------- launcher -------------------------------------------------------
extern "C" void kernel_launch(void* const* d_in, const int* in_sizes, int n_in,
                              void* d_out, int out_size, void* d_ws, size_t ws_size,
                              hipStream_t stream) {
    const float* X  = (const float*)d_in[0];
    const int*   ei = (const int*)d_in[1];
    const float* W  = (const float*)d_in[2];
    const float* b  = (const float*)d_in[3];

    int E = in_sizes[1] / 2;
    const int* nodes  = ei;
    const int* hedges = ei + E;
    int NCH = (E + CHSZ - 1) / CHSZ;       // 196 for E=1.6M (must be <= 256)
    int nsort = 2 * NCH;
    int gemmb = (NN + GROWS - 1) / GROWS;  // 4167

    // workspace layout (~61 MB)
    char* p = (char*)d_ws;
    __half2* xs = (__half2*)p;            p += (size_t)NN * F * 2;            // sliced x, 12.8MB
    __half2* ms = (__half2*)p;            p += (size_t)NM * F * 2;            // sliced m, 12.8MB
    ushort_t* adj0 = (ushort_t*)p;        p += (size_t)E * 2;                 // 3.2MB
    ushort_t* adj1 = (ushort_t*)p;        p += (size_t)E * 2;                 // 3.2MB
    int* ghist  = (int*)p;                p += (size_t)2 * NBUK * NCH * 4;    // 2.45MB
    int* gstart = (int*)p;                p += (size_t)2 * NBUK * NCH * 4;    // 2.45MB
    int* bstart = (int*)p;                p += (size_t)2 * NBUK * 4;
    int* off0   = (int*)p;                p += (size_t)(NN + 1) * 4;
    int* off1   = (int*)p;                p += (size_t)(NN + 1) * 4;
    p = (char*)(((uintptr_t)p + 15) & ~(uintptr_t)15);
    int* gchunk0 = (int*)p;                                                   // NCH*CHSZ ints
    int* gchunk1 = gchunk0 + (size_t)NCH * CHSZ;
    float2* lg = (float2*)gchunk0;        // logits alias gchunk region (dead by agg_b), 25.6MB

    fat_k<<<nsort + gemmb, 256, 0, stream>>>(X, W, xs, nodes, hedges,
                                             gchunk0, gchunk1, ghist, gstart, E, NCH, nsort);
    bucketbase_k<<<2, 1024, 0, stream>>>(ghist, bstart, off0, off1, E, NCH);
    merge_scatter_k<<<2 * NBUK, 256, 0, stream>>>(gchunk0, gchunk1, ghist, gstart, bstart,
                                                  adj0, adj1, off0, off1, NCH);
    agg_a_k<<<8 * ((NM + 31) / 32), 256, 0, stream>>>(xs, adj0, off0, ms);
    agg_b_k<<<8 * ((NN + 31) / 32), 256, 0, stream>>>(ms, adj1, off1, b, lg);
    softmax_k<<<NN / 4, 256, 0, stream>>>(lg, (float2*)d_out);
}